// Round 11
// baseline (39.772 us; speedup 1.0000x reference)
//
#include <hip/hip_runtime.h>
#include <hip/hip_bf16.h>
#include <math.h>

// v10 = v9 + counted-vmcnt depth (T4) + x in registers.
//  - x: per-wave register pipeline (static named regs, depth 1 tile = 64B/lane
//    always in flight; no LDS, no barrier coupling, zero bank conflicts).
//  - w1: TRIPLE-buffered LDS tiles staged via global_load_lds; raw s_barrier +
//    counted "s_waitcnt vmcnt(6)" -> stage for kt+1 has ~2 full phases to land,
//    queue never drains (m201/T4 ledger: 6 VMEM issued per wave per iter).
//  - w2: same 3-buffer rotation through the freed w1 buffers, vmcnt(2/2/0).
//  - weights pre-packed/pre-swizzled bf16 in d_ws (unchanged from v9).
//  - LDS 64KB -> 2 blocks/CU (16 waves/CU). 512 blocks x 512 thr.

#define TPB 512

// packed weights in d_ws (shorts):
//  w1k [13 kt][128 row][8 chunk][8]  (chunk pre-XOR'd by row&7)
//  w2k [4 kt][256 row][4 chunk][8]   (pre-XOR'd by row&3)
//  w3k [16 row][32 chunk][8]         (pre-XOR'd by row&7; rows >=10 zero)
#define W2K 106496
#define W3K 139264
#define NCHUNK_TOT 17920   // 13312 + 4096 + 512 (16B chunks)

typedef __attribute__((ext_vector_type(8))) short bf16x8;
typedef __attribute__((ext_vector_type(4))) float f32x4;

static __device__ inline short f2bf(float f) {
    union { float f; unsigned u; } v; v.f = f;
    unsigned r = v.u + 0x7fffu + ((v.u >> 16) & 1u);   // RNE
    return (short)(r >> 16);
}
static __device__ inline bf16x8 cvt8(float4 a, float4 b) {
    union { __hip_bfloat162 h2[4]; bf16x8 v; } u;
    u.h2[0] = __float22bfloat162_rn(make_float2(a.x, a.y));
    u.h2[1] = __float22bfloat162_rn(make_float2(a.z, a.w));
    u.h2[2] = __float22bfloat162_rn(make_float2(b.x, b.y));
    u.h2[3] = __float22bfloat162_rn(make_float2(b.z, b.w));
    return u.v;
}
static __device__ inline void gld16(const void* g, void* l) {
    __builtin_amdgcn_global_load_lds(
        (const __attribute__((address_space(1))) unsigned int*)g,
        (__attribute__((address_space(3))) unsigned int*)l, 16, 0, 0);
}

__global__ void prep_pack(const float* __restrict__ w1,
                          const float* __restrict__ w2,
                          const float* __restrict__ w3,
                          short* __restrict__ wb) {
    const int tid = blockIdx.x * blockDim.x + threadIdx.x;  // one per 16B chunk
    if (tid >= NCHUNK_TOT) return;
    float4 a = make_float4(0,0,0,0), b = a;
    size_t dst;
    if (tid < 13312) {            // w1k
        const int kt = tid >> 10, rem = tid & 1023, row = rem >> 3, phys = rem & 7;
        const int kg = kt * 64 + ((phys ^ (row & 7)) << 3);
        if (kg + 8 <= 784) {
            const float* p = &w1[(size_t)row * 784 + kg];
            a = *(const float4*)p; b = *(const float4*)(p + 4);
        }
        dst = (size_t)tid * 8;
    } else if (tid < 17408) {     // w2k
        const int t2 = tid - 13312;
        const int kt = t2 >> 10, rem = t2 & 1023, row = rem >> 2, phys = rem & 3;
        const int kg = kt * 32 + ((phys ^ (row & 3)) << 3);
        const float* p = &w2[(size_t)row * 128 + kg];
        a = *(const float4*)p; b = *(const float4*)(p + 4);
        dst = (size_t)W2K + (size_t)t2 * 8;
    } else {                      // w3k
        const int t3 = tid - 17408;
        const int row = t3 >> 5, phys = t3 & 31;
        const int kg = (phys ^ (row & 7)) << 3;
        if (row < 10) {
            const float* p = &w3[(size_t)row * 256 + kg];
            a = *(const float4*)p; b = *(const float4*)(p + 4);
        }
        dst = (size_t)W3K + (size_t)t3 * 8;
    }
    *(bf16x8*)&wb[dst] = cvt8(a, b);
}

__global__ __launch_bounds__(TPB, 4) void mnist_v10(
    const float* __restrict__ x,    // [32768,784]
    const float* __restrict__ b1v,  // [128]
    const float* __restrict__ b2v,  // [256]
    const float* __restrict__ b3v,  // [10]
    const short* __restrict__ wb,   // packed bf16 weights
    float* __restrict__ out)        // [32768,10]
{
    __shared__ __align__(16) char smem[64 * 1024];
    short* const B0  = (short*)smem;               // 16KB buffers (w1/w2 tiles)
    short* const B1  = B0 + 8192;
    short* const B2  = B1 + 8192;
    short* const h1  = B2 + 8192;                  // [64][128] bf16 (16KB)
    short* const h2  = B0;                         // [64][256] overlay (32KB = B0+B1)
    short* const w3l = h1;                         // [16][256] overlay (8KB)

    const int t    = threadIdx.x;
    const int lane = t & 63;
    const int wv   = t >> 6;        // 0..7
    const int mi   = wv >> 1;       // M-tile: local rows mi*16..+15
    const int nh   = wv & 1;        // N-half
    const int l15  = lane & 15;
    const int l4   = lane >> 4;
    const int row0 = blockIdx.x * 64;
    const int arow = 16 * mi + l15;

    const size_t XMAX  = (size_t)32768 * 3136 - 16;
    const size_t xbase = (size_t)(row0 + arow) * 3136;

    auto xld = [&](int kf) -> float4 {             // kf = float index in row
        size_t off = xbase + (size_t)kf * 4;
        off = off > XMAX ? XMAX : off;             // tail clamp (weights zero there)
        return *(const float4*)((const char*)x + off);
    };
    auto stage_w1 = [&](int kt, short* dst) {      // 2 glds/wave, 16KB tile
        #pragma unroll
        for (int p = 0; p < 2; ++p) {
            const int rloc = wv * 16 + p * 8;
            gld16(wb + (size_t)kt * 8192 + rloc * 64 + lane * 8, dst + rloc * 64);
        }
    };
    auto stage_w2 = [&](int kt, short* dst) {      // 2 glds/wave, 16KB tile
        #pragma unroll
        for (int p = 0; p < 2; ++p) {
            const int rloc = wv * 32 + p * 16;
            gld16(wb + W2K + (size_t)kt * 8192 + rloc * 32 + lane * 8, dst + rloc * 32);
        }
    };

    short *b0 = B0, *b1 = B1, *b2 = B2;

    // ---- prologue ledger: [w1(0) x2][x(0) x4][w1(1) x2] -> vmcnt(6) waits w1(0)
    stage_w1(0, b0);
    float4 xc0 = xld(l4 * 8),      xc1 = xld(l4 * 8 + 4);
    float4 xc2 = xld(32 + l4 * 8), xc3 = xld(32 + l4 * 8 + 4);
    stage_w1(1, b1);
    asm volatile("s_waitcnt vmcnt(6)" ::: "memory");
    __builtin_amdgcn_s_barrier();
    __builtin_amdgcn_sched_barrier(0);

    // ---------------- Layer 1: 13 K-tiles of 64, counted-vmcnt pipeline -------
    f32x4 acc1[4];
    #pragma unroll
    for (int nf = 0; nf < 4; ++nf) acc1[nf] = (f32x4){0.f,0.f,0.f,0.f};

    for (int kt = 0; kt < 13; ++kt) {
        float4 xn0, xn1, xn2, xn3;
        if (kt < 12) {                              // 4 VMEM: x for kt+1
            const int kb = (kt + 1) * 64 + l4 * 8;
            xn0 = xld(kb);      xn1 = xld(kb + 4);
            xn2 = xld(kb + 32); xn3 = xld(kb + 36);
        }
        if (kt < 11)      stage_w1(kt + 2, b2);     // 2 VMEM: w1 for kt+2
        else if (kt == 11) stage_w2(0, b2);         // 2 VMEM (b2 free: kt-1 done)
        else               stage_w2(1, b2);         // kt==12

        const bf16x8 a0 = cvt8(xc0, xc1);
        const bf16x8 a1 = cvt8(xc2, xc3);
        #pragma unroll
        for (int nf = 0; nf < 4; ++nf) {
            const int rB = nh * 64 + nf * 16 + l15;
            const bf16x8 w0 = *(const bf16x8*)&b0[rB * 64 + ((l4 ^ (rB & 7)) << 3)];
            const bf16x8 w1f = *(const bf16x8*)&b0[rB * 64 + (((4 + l4) ^ (rB & 7)) << 3)];
            acc1[nf] = __builtin_amdgcn_mfma_f32_16x16x32_bf16(a0, w0, acc1[nf], 0, 0, 0);
            acc1[nf] = __builtin_amdgcn_mfma_f32_16x16x32_bf16(a1, w1f, acc1[nf], 0, 0, 0);
        }
        if (kt < 12) {
            // 6 VMEM issued this iter stay outstanding; waits w1(kt+1) from prev iter
            asm volatile("s_waitcnt vmcnt(6)" ::: "memory");
            __builtin_amdgcn_s_barrier();
            __builtin_amdgcn_sched_barrier(0);
            xc0 = xn0; xc1 = xn1; xc2 = xn2; xc3 = xn3;
        }
        short* tmp = b0; b0 = b1; b1 = b2; b2 = tmp;
    }

    // ---------------- h1 epilogue (disjoint region, no barrier needed first) ---
    #pragma unroll
    for (int nf = 0; nf < 4; ++nf) {
        const int c = nh * 64 + nf * 16 + l15;
        const float bc = b1v[c];
        #pragma unroll
        for (int i = 0; i < 4; ++i) {
            const int r = mi * 16 + l4 * 4 + i;
            const float h = fmaxf(acc1[nf][i] + bc, 0.f);
            h1[r * 128 + (((c >> 3) ^ (r & 7)) << 3) + (c & 7)] = f2bf(h);
        }
    }
    __syncthreads();               // h1 visible; full drain covers w2(0), w2(1)

    bf16x8 a2[4];
    #pragma unroll
    for (int kk = 0; kk < 4; ++kk)
        a2[kk] = *(const bf16x8*)&h1[arow * 128 + (((kk * 4 + l4) ^ (arow & 7)) << 3)];
    __syncthreads();               // h1 region free

    {                              // w3 -> h1 region (consumed at L3, many phases later)
        const int rloc = wv * 2;
        gld16(wb + W3K + rloc * 256 + lane * 8, w3l + rloc * 256);
    }

    // ---------------- Layer 2: 4 K-tiles of 32, counted pipeline --------------
    f32x4 acc2[8];
    #pragma unroll
    for (int nf = 0; nf < 8; ++nf) acc2[nf] = (f32x4){0.f,0.f,0.f,0.f};

    #pragma unroll
    for (int kt2 = 0; kt2 < 4; ++kt2) {
        if (kt2 < 2) stage_w2(kt2 + 2, b2);
        #pragma unroll
        for (int nf = 0; nf < 8; ++nf) {
            const int rB = nh * 128 + nf * 16 + l15;
            const bf16x8 b = *(const bf16x8*)&b0[rB * 32 + ((l4 ^ (rB & 3)) << 3)];
            acc2[nf] = __builtin_amdgcn_mfma_f32_16x16x32_bf16(a2[kt2], b, acc2[nf], 0, 0, 0);
        }
        if (kt2 < 3) {
            if (kt2 == 2) asm volatile("s_waitcnt vmcnt(0)" ::: "memory");
            else          asm volatile("s_waitcnt vmcnt(2)" ::: "memory");
            __builtin_amdgcn_s_barrier();
            __builtin_amdgcn_sched_barrier(0);
        }
        short* tmp = b0; b0 = b1; b1 = b2; b2 = tmp;
    }
    __syncthreads();               // all waves done with tiles before h2 overlay

    // ---------------- h2 epilogue ----------------------------------------------
    #pragma unroll
    for (int nf = 0; nf < 8; ++nf) {
        const int c = nh * 128 + nf * 16 + l15;
        const float bc = b2v[c];
        #pragma unroll
        for (int i = 0; i < 4; ++i) {
            const int r = mi * 16 + l4 * 4 + i;
            const float h = fmaxf(acc2[nf][i] + bc, 0.f);
            h2[r * 256 + (((c >> 3) ^ (r & 7)) << 3) + (c & 7)] = f2bf(h);
        }
    }
    __syncthreads();

    // ---------------- Layer 3 + log_softmax (nh==0 waves) ----------------------
    if (nh == 0) {
        f32x4 acc3 = (f32x4){0.f,0.f,0.f,0.f};
        #pragma unroll
        for (int kt = 0; kt < 8; ++kt) {
            const int slot = kt * 4 + l4;
            const bf16x8 a3  = *(const bf16x8*)&h2[arow * 256 + ((slot ^ (arow & 7)) << 3)];
            const bf16x8 b3r = *(const bf16x8*)&w3l[l15 * 256 + ((slot ^ (l15 & 7)) << 3)];
            acc3 = __builtin_amdgcn_mfma_f32_16x16x32_bf16(a3, b3r, acc3, 0, 0, 0);
        }
        const float b3c = (l15 < 10) ? b3v[l15] : 0.f;
        #pragma unroll
        for (int i = 0; i < 4; ++i) {
            const float v = acc3[i] + b3c;
            float m = (l15 < 10) ? v : -1e30f;
            #pragma unroll
            for (int off = 8; off; off >>= 1) m = fmaxf(m, __shfl_xor(m, off, 16));
            const float e = (l15 < 10) ? expf(v - m) : 0.f;
            float sum = e;
            #pragma unroll
            for (int off = 8; off; off >>= 1) sum += __shfl_xor(sum, off, 16);
            const float ls = m + logf(sum);
            if (l15 < 10) {
                const int r = row0 + mi * 16 + l4 * 4 + i;
                out[(size_t)r * 10 + l15] = v - ls;
            }
        }
    }
}

extern "C" void kernel_launch(void* const* d_in, const int* in_sizes, int n_in,
                              void* d_out, int out_size, void* d_ws, size_t ws_size,
                              hipStream_t stream) {
    const float* x  = (const float*)d_in[0];
    const float* w1 = (const float*)d_in[1];
    const float* b1 = (const float*)d_in[2];
    const float* w2 = (const float*)d_in[3];
    const float* b2 = (const float*)d_in[4];
    const float* w3 = (const float*)d_in[5];
    const float* b3 = (const float*)d_in[6];
    float* out = (float*)d_out;
    short* wb  = (short*)d_ws;   // needs ~287KB scratch

    prep_pack<<<(NCHUNK_TOT + 255) / 256, 256, 0, stream>>>(w1, w2, w3, wb);

    dim3 grid(32768 / 64), block(TPB);
    mnist_v10<<<grid, block, 0, stream>>>(x, b1, b2, b3, wb, out);
}

// Round 12
// 33.967 us; speedup vs baseline: 1.1709x; 1.1709x over previous
//
#include <hip/hip_runtime.h>
#include <hip/hip_bf16.h>
#include <math.h>

// v11 = v9 restored (best measured: 33.4us). v10's counted-vmcnt + x-in-reg
// experiment regressed (39.8) and is reverted.
//  - x staged via global_load_lds with PRE-SWIZZLED GLOBAL SOURCE (m173 /
//    rule #21): LDS stays linear, lane reads x[row][ (lane&15 ^ row&15)*4 ],
//    A-read applies the same XOR -> conflict-light (<=4-way on A, free on B).
//  - weights pre-packed/pre-swizzled bf16 in d_ws by prep_pack.
//  - 512 blocks x 512 thr (8 waves), 80KB LDS -> 2 blocks/CU (16 waves/CU);
//    2-phase stage->MFMA->sync per K-tile; two independent blocks per CU
//    overlap each other's barrier drains.

#define TPB 512

// packed weights in d_ws (shorts):
//  w1k [13 kt][128 row][8 chunk][8]  (chunk pre-XOR'd by row&7)
//  w2k [4 kt][256 row][4 chunk][8]   (pre-XOR'd by row&3)
//  w3k [16 row][32 chunk][8]         (pre-XOR'd by row&7; rows >=10 zero)
#define W2K 106496
#define W3K 139264
#define NCHUNK_TOT 17920   // 13312 + 4096 + 512 (16B chunks)

typedef __attribute__((ext_vector_type(8))) short bf16x8;
typedef __attribute__((ext_vector_type(4))) float f32x4;

static __device__ inline short f2bf(float f) {
    union { float f; unsigned u; } v; v.f = f;
    unsigned r = v.u + 0x7fffu + ((v.u >> 16) & 1u);   // RNE
    return (short)(r >> 16);
}
static __device__ inline bf16x8 cvt8(float4 a, float4 b) {
    union { __hip_bfloat162 h2[4]; bf16x8 v; } u;
    u.h2[0] = __float22bfloat162_rn(make_float2(a.x, a.y));
    u.h2[1] = __float22bfloat162_rn(make_float2(a.z, a.w));
    u.h2[2] = __float22bfloat162_rn(make_float2(b.x, b.y));
    u.h2[3] = __float22bfloat162_rn(make_float2(b.z, b.w));
    return u.v;
}
static __device__ inline void gld16(const void* g, void* l) {
    __builtin_amdgcn_global_load_lds(
        (const __attribute__((address_space(1))) unsigned int*)g,
        (__attribute__((address_space(3))) unsigned int*)l, 16, 0, 0);
}

__global__ void prep_pack(const float* __restrict__ w1,
                          const float* __restrict__ w2,
                          const float* __restrict__ w3,
                          short* __restrict__ wb) {
    const int tid = blockIdx.x * blockDim.x + threadIdx.x;  // one per 16B chunk
    if (tid >= NCHUNK_TOT) return;
    float4 a = make_float4(0,0,0,0), b = a;
    size_t dst;
    if (tid < 13312) {            // w1k
        const int kt = tid >> 10, rem = tid & 1023, row = rem >> 3, phys = rem & 7;
        const int kg = kt * 64 + ((phys ^ (row & 7)) << 3);
        if (kg + 8 <= 784) {
            const float* p = &w1[(size_t)row * 784 + kg];
            a = *(const float4*)p; b = *(const float4*)(p + 4);
        }
        dst = (size_t)tid * 8;
    } else if (tid < 17408) {     // w2k
        const int t2 = tid - 13312;
        const int kt = t2 >> 10, rem = t2 & 1023, row = rem >> 2, phys = rem & 3;
        const int kg = kt * 32 + ((phys ^ (row & 3)) << 3);
        const float* p = &w2[(size_t)row * 128 + kg];
        a = *(const float4*)p; b = *(const float4*)(p + 4);
        dst = (size_t)W2K + (size_t)t2 * 8;
    } else {                      // w3k
        const int t3 = tid - 17408;
        const int row = t3 >> 5, phys = t3 & 31;
        const int kg = (phys ^ (row & 7)) << 3;
        if (row < 10) {
            const float* p = &w3[(size_t)row * 256 + kg];
            a = *(const float4*)p; b = *(const float4*)(p + 4);
        }
        dst = (size_t)W3K + (size_t)t3 * 8;
    }
    *(bf16x8*)&wb[dst] = cvt8(a, b);
}

__global__ __launch_bounds__(TPB, 4) void mnist_v11(
    const float* __restrict__ x,    // [32768,784]
    const float* __restrict__ b1v,  // [128]
    const float* __restrict__ b2v,  // [256]
    const float* __restrict__ b3v,  // [10]
    const short* __restrict__ wb,   // packed bf16 weights
    float* __restrict__ out)        // [32768,10]
{
    __shared__ __align__(16) char smem[80 * 1024];
    float* const xb  = (float*)smem;               // [2][64][64] f32 (32KB), src-swizzled
    short* const wbf = (short*)(smem + 32 * 1024); // [2][128][64] bf16 (32KB)
    short* const h1  = (short*)(smem + 64 * 1024); // [64][128] bf16 (16KB)
    short* const w2l = (short*)smem;               // L2 overlay: [2][256][32] in xb region
    short* const h2  = wbf;                        // [64][256] bf16 overlay (32KB)
    short* const w3l = h1;                         // [16][256] bf16 overlay (8KB)

    const int t    = threadIdx.x;
    const int lane = t & 63;
    const int wv   = t >> 6;        // 0..7
    const int mi   = wv >> 1;       // M-tile: local rows mi*16..+15
    const int nh   = wv & 1;        // N-half
    const int l15  = lane & 15;
    const int l4   = lane >> 4;
    const int row0 = blockIdx.x * 64;

    const size_t XLAST = (size_t)32768 * 3136 - 16;

    // --- staging (glds dest = wave-uniform base + lane*16, LDS linear) -------
    // x: LDS[lrow][slot] holds x[row0+lrow][kt*64 + (slot ^ (lrow&15))*4 ..+4)
    auto stage_x = [&](int kt, float* dst) {
        #pragma unroll
        for (int p = 0; p < 2; ++p) {
            const int rloc = wv * 8 + p * 4;          // 4 rows per glds
            const int rl   = rloc + (lane >> 4);      // this lane's local row
            const int logs = (lane & 15) ^ (rl & 15); // pre-swizzled source slot
            size_t off = (size_t)(row0 + rl) * 3136 + (size_t)kt * 256
                       + (size_t)logs * 16;
            if (off > XLAST) off = XLAST;             // final-row tail clamp
            gld16((const char*)x + off, dst + rloc * 64);
        }
    };
    auto stage_w1 = [&](int kt, short* dst) {
        #pragma unroll
        for (int p = 0; p < 2; ++p) {
            const int rloc = wv * 16 + p * 8;
            gld16(wb + (size_t)kt * 8192 + rloc * 64 + lane * 8, dst + rloc * 64);
        }
    };
    auto stage_w2 = [&](int kt, short* dst) {
        #pragma unroll
        for (int p = 0; p < 2; ++p) {
            const int rloc = wv * 32 + p * 16;
            gld16(wb + W2K + (size_t)kt * 8192 + rloc * 32 + lane * 8, dst + rloc * 32);
        }
    };

    // ---------------- prologue: tile 0 ----------------------------------------
    stage_x(0, xb);
    stage_w1(0, wbf);
    __syncthreads();

    // ---------------- Layer 1: 13 K-tiles of 64 -------------------------------
    f32x4 acc1[4];
    #pragma unroll
    for (int nf = 0; nf < 4; ++nf) acc1[nf] = (f32x4){0.f,0.f,0.f,0.f};

    const int arow = 16 * mi + l15;                   // local A row; arow&15 == l15
    for (int kt = 0; kt < 13; ++kt) {
        const int cur = kt & 1;
        if (kt < 12) {
            stage_x(kt + 1, xb + (cur ^ 1) * 4096);
            stage_w1(kt + 1, wbf + (cur ^ 1) * 8192);
        }
        const float* xt = xb + cur * 4096;
        const short* wt = wbf + cur * 8192;
        #pragma unroll
        for (int kk = 0; kk < 2; ++kk) {
            const int s0 = kk * 8 + l4 * 2;           // logical 16B slot of frag start
            const float4 fa = *(const float4*)&xt[arow * 64 + ((s0 ^ l15) << 2)];
            const float4 fb = *(const float4*)&xt[arow * 64 + (((s0 + 1) ^ l15) << 2)];
            const bf16x8 a = cvt8(fa, fb);
            #pragma unroll
            for (int nf = 0; nf < 4; ++nf) {
                const int rB = nh * 64 + nf * 16 + l15;
                const int phys = (kk * 4 + l4) ^ (rB & 7);
                const bf16x8 b = *(const bf16x8*)&wt[rB * 64 + phys * 8];
                acc1[nf] = __builtin_amdgcn_mfma_f32_16x16x32_bf16(a, b, acc1[nf], 0, 0, 0);
            }
        }
        __syncthreads();
    }

    // ---------------- L1 epilogue + prefetch w2 t0/t1 --------------------------
    stage_w2(0, w2l);
    stage_w2(1, w2l + 8192);
    #pragma unroll
    for (int nf = 0; nf < 4; ++nf) {
        const int c = nh * 64 + nf * 16 + l15;
        const float bc = b1v[c];
        #pragma unroll
        for (int i = 0; i < 4; ++i) {
            const int r = mi * 16 + l4 * 4 + i;
            const float h = fmaxf(acc1[nf][i] + bc, 0.f);
            h1[r * 128 + (((c >> 3) ^ (r & 7)) << 3) + (c & 7)] = f2bf(h);
        }
    }
    __syncthreads();               // h1 visible; w2 t0/t1 drained

    // ---------------- Layer 2: 4 K-tiles of 32 --------------------------------
    bf16x8 a2[4];
    {
        #pragma unroll
        for (int kk = 0; kk < 4; ++kk)
            a2[kk] = *(const bf16x8*)&h1[arow * 128 + (((kk * 4 + l4) ^ (arow & 7)) << 3)];
    }
    __syncthreads();               // all waves read a2 -> h1 region dead

    // w3 into h1 region (used in L3; drained by kt0's barrier)
    {
        const int rloc = wv * 2;
        gld16(wb + W3K + rloc * 256 + lane * 8, w3l + rloc * 256);
    }

    f32x4 acc2[8];
    #pragma unroll
    for (int nf = 0; nf < 8; ++nf) acc2[nf] = (f32x4){0.f,0.f,0.f,0.f};

    #pragma unroll
    for (int kt = 0; kt < 4; ++kt) {
        const short* wt2 = w2l + (kt & 1) * 8192;
        #pragma unroll
        for (int nf = 0; nf < 8; ++nf) {
            const int rB = nh * 128 + nf * 16 + l15;
            const int phys = l4 ^ (rB & 3);
            const bf16x8 b = *(const bf16x8*)&wt2[rB * 32 + phys * 8];
            acc2[nf] = __builtin_amdgcn_mfma_f32_16x16x32_bf16(a2[kt], b, acc2[nf], 0, 0, 0);
        }
        __syncthreads();           // all waves done with tile kt (drains stages)
        if (kt < 2)
            stage_w2(kt + 2, w2l + (kt & 1) * 8192);
    }

    // ---------------- h2 epilogue ----------------------------------------------
    #pragma unroll
    for (int nf = 0; nf < 8; ++nf) {
        const int c = nh * 128 + nf * 16 + l15;
        const float bc = b2v[c];
        #pragma unroll
        for (int i = 0; i < 4; ++i) {
            const int r = mi * 16 + l4 * 4 + i;
            const float h = fmaxf(acc2[nf][i] + bc, 0.f);
            h2[r * 256 + (((c >> 3) ^ (r & 7)) << 3) + (c & 7)] = f2bf(h);
        }
    }
    __syncthreads();

    // ---------------- Layer 3 + log_softmax (nh==0 waves) ----------------------
    if (nh == 0) {
        f32x4 acc3 = (f32x4){0.f,0.f,0.f,0.f};
        #pragma unroll
        for (int kt = 0; kt < 8; ++kt) {
            const int slot = kt * 4 + l4;
            const bf16x8 a3  = *(const bf16x8*)&h2[arow * 256 + ((slot ^ (arow & 7)) << 3)];
            const bf16x8 b3r = *(const bf16x8*)&w3l[l15 * 256 + ((slot ^ (l15 & 7)) << 3)];
            acc3 = __builtin_amdgcn_mfma_f32_16x16x32_bf16(a3, b3r, acc3, 0, 0, 0);
        }
        const float b3c = (l15 < 10) ? b3v[l15] : 0.f;
        #pragma unroll
        for (int i = 0; i < 4; ++i) {
            const float v = acc3[i] + b3c;
            float m = (l15 < 10) ? v : -1e30f;
            #pragma unroll
            for (int off = 8; off; off >>= 1) m = fmaxf(m, __shfl_xor(m, off, 16));
            const float e = (l15 < 10) ? expf(v - m) : 0.f;
            float sum = e;
            #pragma unroll
            for (int off = 8; off; off >>= 1) sum += __shfl_xor(sum, off, 16);
            const float ls = m + logf(sum);
            if (l15 < 10) {
                const int r = row0 + mi * 16 + l4 * 4 + i;
                out[(size_t)r * 10 + l15] = v - ls;
            }
        }
    }
}

extern "C" void kernel_launch(void* const* d_in, const int* in_sizes, int n_in,
                              void* d_out, int out_size, void* d_ws, size_t ws_size,
                              hipStream_t stream) {
    const float* x  = (const float*)d_in[0];
    const float* w1 = (const float*)d_in[1];
    const float* b1 = (const float*)d_in[2];
    const float* w2 = (const float*)d_in[3];
    const float* b2 = (const float*)d_in[4];
    const float* w3 = (const float*)d_in[5];
    const float* b3 = (const float*)d_in[6];
    float* out = (float*)d_out;
    short* wb  = (short*)d_ws;   // needs ~287KB scratch

    prep_pack<<<(NCHUNK_TOT + 255) / 256, 256, 0, stream>>>(w1, w2, w3, wb);

    dim3 grid(32768 / 64), block(TPB);
    mnist_v11<<<grid, block, 0, stream>>>(x, b1, b2, b3, wb, out);
}

// Round 13
// 33.807 us; speedup vs baseline: 1.1764x; 1.0047x over previous
//
#include <hip/hip_runtime.h>
#include <hip/hip_bf16.h>
#include <math.h>

// v12 = v11 (best: 33.4-34.0us) + single-phase Layer 2.
//  - After the L1 loop both xb and wbf LDS regions (64KB) are dead; the FULL
//    w2 (4 tiles x 16KB) is staged there in one glds burst issued before the
//    h1 epilogue -> its latency hides under epilogue + a2-read + barrier.
//    Layer 2 then runs all 32 MFMAs with zero intermediate barriers.
//    Sync points: 21 -> 17. Everything else identical to v11.
//  - x staged via global_load_lds with pre-swizzled global source (rule #21);
//    weights pre-packed/pre-swizzled bf16 in d_ws by prep_pack.
//  - 512 blocks x 512 thr (8 waves), 80KB LDS -> 2 blocks/CU (16 waves/CU).

#define TPB 512

// packed weights in d_ws (shorts):
//  w1k [13 kt][128 row][8 chunk][8]  (chunk pre-XOR'd by row&7)
//  w2k [4 kt][256 row][4 chunk][8]   (pre-XOR'd by row&3)
//  w3k [16 row][32 chunk][8]         (pre-XOR'd by row&7; rows >=10 zero)
#define W2K 106496
#define W3K 139264
#define NCHUNK_TOT 17920   // 13312 + 4096 + 512 (16B chunks)

typedef __attribute__((ext_vector_type(8))) short bf16x8;
typedef __attribute__((ext_vector_type(4))) float f32x4;

static __device__ inline short f2bf(float f) {
    union { float f; unsigned u; } v; v.f = f;
    unsigned r = v.u + 0x7fffu + ((v.u >> 16) & 1u);   // RNE
    return (short)(r >> 16);
}
static __device__ inline bf16x8 cvt8(float4 a, float4 b) {
    union { __hip_bfloat162 h2[4]; bf16x8 v; } u;
    u.h2[0] = __float22bfloat162_rn(make_float2(a.x, a.y));
    u.h2[1] = __float22bfloat162_rn(make_float2(a.z, a.w));
    u.h2[2] = __float22bfloat162_rn(make_float2(b.x, b.y));
    u.h2[3] = __float22bfloat162_rn(make_float2(b.z, b.w));
    return u.v;
}
static __device__ inline void gld16(const void* g, void* l) {
    __builtin_amdgcn_global_load_lds(
        (const __attribute__((address_space(1))) unsigned int*)g,
        (__attribute__((address_space(3))) unsigned int*)l, 16, 0, 0);
}

__global__ void prep_pack(const float* __restrict__ w1,
                          const float* __restrict__ w2,
                          const float* __restrict__ w3,
                          short* __restrict__ wb) {
    const int tid = blockIdx.x * blockDim.x + threadIdx.x;  // one per 16B chunk
    if (tid >= NCHUNK_TOT) return;
    float4 a = make_float4(0,0,0,0), b = a;
    size_t dst;
    if (tid < 13312) {            // w1k
        const int kt = tid >> 10, rem = tid & 1023, row = rem >> 3, phys = rem & 7;
        const int kg = kt * 64 + ((phys ^ (row & 7)) << 3);
        if (kg + 8 <= 784) {
            const float* p = &w1[(size_t)row * 784 + kg];
            a = *(const float4*)p; b = *(const float4*)(p + 4);
        }
        dst = (size_t)tid * 8;
    } else if (tid < 17408) {     // w2k
        const int t2 = tid - 13312;
        const int kt = t2 >> 10, rem = t2 & 1023, row = rem >> 2, phys = rem & 3;
        const int kg = kt * 32 + ((phys ^ (row & 3)) << 3);
        const float* p = &w2[(size_t)row * 128 + kg];
        a = *(const float4*)p; b = *(const float4*)(p + 4);
        dst = (size_t)W2K + (size_t)t2 * 8;
    } else {                      // w3k
        const int t3 = tid - 17408;
        const int row = t3 >> 5, phys = t3 & 31;
        const int kg = (phys ^ (row & 7)) << 3;
        if (row < 10) {
            const float* p = &w3[(size_t)row * 256 + kg];
            a = *(const float4*)p; b = *(const float4*)(p + 4);
        }
        dst = (size_t)W3K + (size_t)t3 * 8;
    }
    *(bf16x8*)&wb[dst] = cvt8(a, b);
}

__global__ __launch_bounds__(TPB, 4) void mnist_v12(
    const float* __restrict__ x,    // [32768,784]
    const float* __restrict__ b1v,  // [128]
    const float* __restrict__ b2v,  // [256]
    const float* __restrict__ b3v,  // [10]
    const short* __restrict__ wb,   // packed bf16 weights
    float* __restrict__ out)        // [32768,10]
{
    __shared__ __align__(16) char smem[80 * 1024];
    float* const xb  = (float*)smem;               // [2][64][64] f32 (32KB), src-swizzled
    short* const wbf = (short*)(smem + 32 * 1024); // [2][128][64] bf16 (32KB)
    short* const h1  = (short*)(smem + 64 * 1024); // [64][128] bf16 (16KB)
    short* const w2f = (short*)smem;               // L2 overlay: full w2 [4][256][32] (64KB)
    short* const h2  = (short*)smem;               // [64][256] bf16 overlay (32KB, post-L2)
    short* const w3l = h1;                         // [16][256] overlay (8KB)

    const int t    = threadIdx.x;
    const int lane = t & 63;
    const int wv   = t >> 6;        // 0..7
    const int mi   = wv >> 1;       // M-tile: local rows mi*16..+15
    const int nh   = wv & 1;        // N-half
    const int l15  = lane & 15;
    const int l4   = lane >> 4;
    const int row0 = blockIdx.x * 64;

    const size_t XLAST = (size_t)32768 * 3136 - 16;

    // --- staging (glds dest = wave-uniform base + lane*16, LDS linear) -------
    // x: LDS[lrow][slot] holds x[row0+lrow][kt*64 + (slot ^ (lrow&15))*4 ..+4)
    auto stage_x = [&](int kt, float* dst) {
        #pragma unroll
        for (int p = 0; p < 2; ++p) {
            const int rloc = wv * 8 + p * 4;          // 4 rows per glds
            const int rl   = rloc + (lane >> 4);      // this lane's local row
            const int logs = (lane & 15) ^ (rl & 15); // pre-swizzled source slot
            size_t off = (size_t)(row0 + rl) * 3136 + (size_t)kt * 256
                       + (size_t)logs * 16;
            if (off > XLAST) off = XLAST;             // final-row tail clamp
            gld16((const char*)x + off, dst + rloc * 64);
        }
    };
    auto stage_w1 = [&](int kt, short* dst) {
        #pragma unroll
        for (int p = 0; p < 2; ++p) {
            const int rloc = wv * 16 + p * 8;
            gld16(wb + (size_t)kt * 8192 + rloc * 64 + lane * 8, dst + rloc * 64);
        }
    };

    // ---------------- prologue: tile 0 ----------------------------------------
    stage_x(0, xb);
    stage_w1(0, wbf);
    __syncthreads();

    // ---------------- Layer 1: 13 K-tiles of 64 -------------------------------
    f32x4 acc1[4];
    #pragma unroll
    for (int nf = 0; nf < 4; ++nf) acc1[nf] = (f32x4){0.f,0.f,0.f,0.f};

    const int arow = 16 * mi + l15;                   // local A row; arow&15 == l15
    for (int kt = 0; kt < 13; ++kt) {
        const int cur = kt & 1;
        if (kt < 12) {
            stage_x(kt + 1, xb + (cur ^ 1) * 4096);
            stage_w1(kt + 1, wbf + (cur ^ 1) * 8192);
        }
        const float* xt = xb + cur * 4096;
        const short* wt = wbf + cur * 8192;
        #pragma unroll
        for (int kk = 0; kk < 2; ++kk) {
            const int s0 = kk * 8 + l4 * 2;           // logical 16B slot of frag start
            const float4 fa = *(const float4*)&xt[arow * 64 + ((s0 ^ l15) << 2)];
            const float4 fb = *(const float4*)&xt[arow * 64 + (((s0 + 1) ^ l15) << 2)];
            const bf16x8 a = cvt8(fa, fb);
            #pragma unroll
            for (int nf = 0; nf < 4; ++nf) {
                const int rB = nh * 64 + nf * 16 + l15;
                const int phys = (kk * 4 + l4) ^ (rB & 7);
                const bf16x8 b = *(const bf16x8*)&wt[rB * 64 + phys * 8];
                acc1[nf] = __builtin_amdgcn_mfma_f32_16x16x32_bf16(a, b, acc1[nf], 0, 0, 0);
            }
        }
        __syncthreads();
    }
    // both xb and wbf (64KB) are now dead.

    // ---------------- stage FULL w2 (one burst) + h1 epilogue ------------------
    #pragma unroll
    for (int kt = 0; kt < 4; ++kt) {
        #pragma unroll
        for (int p = 0; p < 2; ++p) {
            const int rloc = wv * 32 + p * 16;
            gld16(wb + W2K + (size_t)kt * 8192 + rloc * 32 + lane * 8,
                  w2f + kt * 8192 + rloc * 32);
        }
    }
    #pragma unroll
    for (int nf = 0; nf < 4; ++nf) {
        const int c = nh * 64 + nf * 16 + l15;
        const float bc = b1v[c];
        #pragma unroll
        for (int i = 0; i < 4; ++i) {
            const int r = mi * 16 + l4 * 4 + i;
            const float h = fmaxf(acc1[nf][i] + bc, 0.f);
            h1[r * 128 + (((c >> 3) ^ (r & 7)) << 3) + (c & 7)] = f2bf(h);
        }
    }
    __syncthreads();               // B: h1 visible, w2f drained

    bf16x8 a2[4];
    #pragma unroll
    for (int kk = 0; kk < 4; ++kk)
        a2[kk] = *(const bf16x8*)&h1[arow * 128 + (((kk * 4 + l4) ^ (arow & 7)) << 3)];
    __syncthreads();               // C: h1 region free

    {                              // w3 -> h1 region (drained at barrier D)
        const int rloc = wv * 2;
        gld16(wb + W3K + rloc * 256 + lane * 8, w3l + rloc * 256);
    }

    // ---------------- Layer 2: 32 MFMAs, no intermediate barriers --------------
    f32x4 acc2[8];
    #pragma unroll
    for (int nf = 0; nf < 8; ++nf) acc2[nf] = (f32x4){0.f,0.f,0.f,0.f};

    #pragma unroll
    for (int kt2 = 0; kt2 < 4; ++kt2) {
        const short* wt2 = w2f + kt2 * 8192;
        #pragma unroll
        for (int nf = 0; nf < 8; ++nf) {
            const int rB = nh * 128 + nf * 16 + l15;
            const bf16x8 b = *(const bf16x8*)&wt2[rB * 32 + ((l4 ^ (rB & 3)) << 3)];
            acc2[nf] = __builtin_amdgcn_mfma_f32_16x16x32_bf16(a2[kt2], b, acc2[nf], 0, 0, 0);
        }
    }
    __syncthreads();               // D: w2f dead, w3 drained

    // ---------------- h2 epilogue (overlay on w2f[0:32K)) ----------------------
    #pragma unroll
    for (int nf = 0; nf < 8; ++nf) {
        const int c = nh * 128 + nf * 16 + l15;
        const float bc = b2v[c];
        #pragma unroll
        for (int i = 0; i < 4; ++i) {
            const int r = mi * 16 + l4 * 4 + i;
            const float h = fmaxf(acc2[nf][i] + bc, 0.f);
            h2[r * 256 + (((c >> 3) ^ (r & 7)) << 3) + (c & 7)] = f2bf(h);
        }
    }
    __syncthreads();               // E: h2 visible

    // ---------------- Layer 3 + log_softmax (nh==0 waves) ----------------------
    if (nh == 0) {
        f32x4 acc3 = (f32x4){0.f,0.f,0.f,0.f};
        #pragma unroll
        for (int kt = 0; kt < 8; ++kt) {
            const int slot = kt * 4 + l4;
            const bf16x8 a3  = *(const bf16x8*)&h2[arow * 256 + ((slot ^ (arow & 7)) << 3)];
            const bf16x8 b3r = *(const bf16x8*)&w3l[l15 * 256 + ((slot ^ (l15 & 7)) << 3)];
            acc3 = __builtin_amdgcn_mfma_f32_16x16x32_bf16(a3, b3r, acc3, 0, 0, 0);
        }
        const float b3c = (l15 < 10) ? b3v[l15] : 0.f;
        #pragma unroll
        for (int i = 0; i < 4; ++i) {
            const float v = acc3[i] + b3c;
            float m = (l15 < 10) ? v : -1e30f;
            #pragma unroll
            for (int off = 8; off; off >>= 1) m = fmaxf(m, __shfl_xor(m, off, 16));
            const float e = (l15 < 10) ? expf(v - m) : 0.f;
            float sum = e;
            #pragma unroll
            for (int off = 8; off; off >>= 1) sum += __shfl_xor(sum, off, 16);
            const float ls = m + logf(sum);
            if (l15 < 10) {
                const int r = row0 + mi * 16 + l4 * 4 + i;
                out[(size_t)r * 10 + l15] = v - ls;
            }
        }
    }
}

extern "C" void kernel_launch(void* const* d_in, const int* in_sizes, int n_in,
                              void* d_out, int out_size, void* d_ws, size_t ws_size,
                              hipStream_t stream) {
    const float* x  = (const float*)d_in[0];
    const float* w1 = (const float*)d_in[1];
    const float* b1 = (const float*)d_in[2];
    const float* w2 = (const float*)d_in[3];
    const float* b2 = (const float*)d_in[4];
    const float* w3 = (const float*)d_in[5];
    const float* b3 = (const float*)d_in[6];
    float* out = (float*)d_out;
    short* wb  = (short*)d_ws;   // needs ~287KB scratch

    prep_pack<<<(NCHUNK_TOT + 255) / 256, 256, 0, stream>>>(w1, w2, w3, wb);

    dim3 grid(32768 / 64), block(TPB);
    mnist_v12<<<grid, block, 0, stream>>>(x, b1, b2, b3, wb, out);
}